// Round 22
// baseline (121.363 us; speedup 1.0000x reference)
//
#include <hip/hip_runtime.h>
#include <hip/hip_bf16.h>
#include <stdint.h>

// B=2, S=2048, D=1024, H=16, DH=64. Causal self-attention block, bf16 MFMA pipeline.

typedef __attribute__((ext_vector_type(8))) short bf16x8;   // 8 bf16 = 16B (A/B frag)
typedef __attribute__((ext_vector_type(4))) float f32x4;    // C/D frag 16x16
typedef __attribute__((ext_vector_type(16))) float f32x16;  // C/D frag 32x32
typedef __attribute__((ext_vector_type(4))) unsigned int u32x4;

typedef const __attribute__((address_space(1))) uint32_t* gp1_t;
typedef __attribute__((address_space(3))) uint32_t* lp3_t;

// v_cvt_pk_bf16_f32: dst.lo = bf16(lo), dst.hi = bf16(hi)  (RNE, 1 VALU op)
static __device__ __forceinline__ uint32_t cvtpk(float lo, float hi) {
  uint32_t r;
  asm("v_cvt_pk_bf16_f32 %0, %1, %2" : "=v"(r) : "v"(lo), "v"(hi));
  return r;
}
// single-value f32->bf16 in ONE instruction (low half of cvt_pk)
static __device__ __forceinline__ uint16_t f2b(float x) {
  return (uint16_t)cvtpk(x, x);
}
// raw hardware exp2 (1 VALU op; underflow flushes to 0 — fine for masked -1e30)
static __device__ __forceinline__ float fexp2(float x) {
  float r;
  asm("v_exp_f32 %0, %1" : "=v"(r) : "v"(x));
  return r;
}

// Stage rows x 64 bf16 (128B = 8 chunks of 16B) tile into LDS, async DMA.
// THR participating threads (contiguous 64-lane waves); covers ISSUES*THR chunks.
template <int ISSUES, int THR = 256>
static __device__ __forceinline__ void stage64(const uint16_t* __restrict__ g, int gstride,
                                               uint8_t* lds, int t) {
#pragma unroll
  for (int i = 0; i < ISSUES; ++i) {
    int p = i * THR + t;          // 16B-chunk index
    int row = p >> 3, c = p & 7;
    const uint16_t* src = g + row * gstride + ((c ^ (row & 7)) << 3);
    __builtin_amdgcn_global_load_lds((gp1_t)src, (lp3_t)(lds + (p & ~63) * 16), 16, 0, 0);
  }
}

// Read a 16B fragment from a swizzled [R][64] bf16 tile: 8 bf16 at (row, chunk*8).
static __device__ __forceinline__ bf16x8 ld_frag(const uint8_t* lds, int row, int chunk) {
  return *(const bf16x8*)(lds + row * 128 + (((chunk) ^ (row & 7)) << 4));
}

// ---------------- f32 -> bf16 convert (x, w_in, w_out fused in one launch) ----------------
__global__ __launch_bounds__(256) void cvt3(const float* __restrict__ a,
                                            const float* __restrict__ b,
                                            const float* __restrict__ c,
                                            uint16_t* __restrict__ oa,
                                            uint16_t* __restrict__ ob,
                                            uint16_t* __restrict__ oc) {
  int i = blockIdx.x * 256 + threadIdx.x;   // in float4 units
  const float* src;
  uint16_t* dst;
  int j;
  if (i < 1048576)      { src = a; dst = oa; j = i; }
  else if (i < 1835008) { src = b; dst = ob; j = i - 1048576; }
  else                  { src = c; dst = oc; j = i - 1835008; }
  float4 v = ((const float4*)src)[j];
  uint2 o;
  o.x = cvtpk(v.x, v.y);
  o.y = cvtpk(v.z, v.w);
  ((uint2*)dst)[j] = o;
}

// ---------------- GEMM1: qkv = x @ w_in^T + b_in ----------------
// BM=128, BN=64 (one head per block -> section-uniform epilogue), BK=64.
// Double-buffered LDS (24KB/buf, 48KB total -> 3 blocks/CU resident), ONE barrier
// per K-step (r18-proven). XCD swizzle: each XCD owns 4 contiguous by-rows.
__global__ __launch_bounds__(256) void gemm_qkv(const uint16_t* __restrict__ A,
                                                const uint16_t* __restrict__ W,
                                                const float* __restrict__ bias,
                                                uint16_t* __restrict__ Qb,
                                                uint16_t* __restrict__ Kb,
                                                uint16_t* __restrict__ Vt) {
  __shared__ uint8_t smraw[49152];     // 2 x (A 16KB + B 8KB); epilogue ot aliases
  int t = threadIdx.x, l = t & 63, w = t >> 6;
  // XCD-bijective remap (nwg=1536, %8==0): each XCD -> 4 contiguous by rows.
  int bid = (int)blockIdx.x + 48 * (int)blockIdx.y;
  int virt = (bid & 7) * 192 + (bid >> 3);
  int bx = virt % 48, by = virt / 48;
  int m0 = by * 128, n0 = bx * 64;
  int wr = (w >> 1) * 64, wc = (w & 1) * 32;
  const f32x4 fz = {0.f, 0.f, 0.f, 0.f};
  f32x4 acc[4][2];
#pragma unroll
  for (int i = 0; i < 4; ++i)
#pragma unroll
    for (int j = 0; j < 2; ++j) acc[i][j] = fz;

  const uint16_t* Ab_ = A + m0 * 1024;
  const uint16_t* Wb_ = W + n0 * 1024;
  stage64<4>(Ab_, 1024, smraw, t);
  stage64<2>(Wb_, 1024, smraw + 16384, t);

  for (int kt = 0; kt < 16; ++kt) {
    int cur = kt & 1;
    uint8_t* curb = smraw + cur * 24576;
    asm volatile("s_waitcnt vmcnt(0)" ::: "memory");  // my DMA landed
    __syncthreads();                                   // all landed; other buf free
    if (kt + 1 < 16) {
      uint8_t* nb = smraw + (cur ^ 1) * 24576;
      stage64<4>(Ab_ + (kt + 1) * 64, 1024, nb, t);
      stage64<2>(Wb_ + (kt + 1) * 64, 1024, nb + 16384, t);
    }
#pragma unroll
    for (int ks = 0; ks < 2; ++ks) {
      bf16x8 a[4], b[2];
#pragma unroll
      for (int i = 0; i < 4; ++i)
        a[i] = ld_frag(curb, wr + i * 16 + (l & 15), ks * 4 + (l >> 4));
#pragma unroll
      for (int j = 0; j < 2; ++j)
        b[j] = ld_frag(curb + 16384, wc + j * 16 + (l & 15), ks * 4 + (l >> 4));
#pragma unroll
      for (int i = 0; i < 4; ++i)
#pragma unroll
        for (int j = 0; j < 2; ++j)
          acc[i][j] = __builtin_amdgcn_mfma_f32_16x16x32_bf16(a[i], b[j], acc[i][j], 0, 0, 0);
    }
  }

  // ---- epilogue: acc -> LDS ----
  __syncthreads();                       // staging dead; reuse as ot
  uint16_t* ot = (uint16_t*)smraw;       // Q/K: [row][72]; V: [col][136] transposed
  const float CSQ = 0.18033688011112042f;  // 0.125 * log2(e)
  int sec = n0 >> 10;                    // block-uniform: 0=Q 1=K 2=V
#pragma unroll
  for (int j = 0; j < 2; ++j) {
    int col = wc + j * 16 + (l & 15);    // 0..63
    float bv = bias[n0 + col];
#pragma unroll
    for (int i = 0; i < 4; ++i) {
      int rb = wr + i * 16 + ((l >> 4) << 2);
#pragma unroll
      for (int r = 0; r < 4; ++r) {
        int row = rb + r;                // 0..127
        float v = acc[i][j][r] + bv;
        if (sec == 0) v *= CSQ;
        if (sec == 2) {
          int rowp = (row & ~12) | ((row & 4) << 1) | ((row & 8) >> 1);  // s bits 2<->3
          ot[col * 136 + rowp] = f2b(v); // transposed for V
        } else {
          ot[row * 72 + col] = f2b(v);
        }
      }
    }
  }
  __syncthreads();

  // ---- coalesced stores (block = one head) ----
  int bb0 = m0 >> 11, sbase = m0 & 2047;
  int h = (n0 & 1023) >> 6;
  if (sec < 2) {
    uint16_t* dst0 = (sec == 0) ? Qb : Kb;
    int s_loc = t >> 1, half = t & 1;
    const uint16_t* src = ot + s_loc * 72 + half * 32;
    uint16_t* dst = dst0 + (((size_t)((bb0 * 16 + h) * 2048 + sbase + s_loc)) << 6) + half * 32;
#pragma unroll
    for (int c = 0; c < 4; ++c)
      *(u32x4*)(dst + c * 8) = *(const u32x4*)(src + c * 8);
  } else {
    int dh = t >> 2, qr = t & 3;
    const uint16_t* src = ot + dh * 136 + qr * 32;
    uint16_t* dst = Vt + ((size_t)((bb0 * 16 + h) * 64 + dh)) * 2048 + sbase + qr * 32;
#pragma unroll
    for (int c = 0; c < 4; ++c)
      *(u32x4*)(dst + c * 8) = *(const u32x4*)(src + c * 8);
  }
}

// ---------------- GEMM2: out = att @ w_out^T + b_out (f32 out) ----------------
// BM=128, BN=64, BK=64 dbuf (48KB), grid (16,32)=512 -> 2 blocks/CU resident.
__global__ __launch_bounds__(256) void gemm_out(const uint16_t* __restrict__ A,
                                                const uint16_t* __restrict__ W,
                                                const float* __restrict__ bias,
                                                float* __restrict__ out) {
  __shared__ uint8_t sm[49152];          // 2 x (A 16KB + B 8KB)
  int t = threadIdx.x, l = t & 63, w = t >> 6;
  int bid = (int)blockIdx.x + 16 * (int)blockIdx.y;
  int virt = (bid & 7) * 64 + (bid >> 3);
  int bx = virt % 16, by = virt / 16;
  int m0 = by * 128, n0 = bx * 64;
  int wr = (w >> 1) * 64, wc = (w & 1) * 32;
  const f32x4 fz = {0.f, 0.f, 0.f, 0.f};
  f32x4 acc[4][2];
#pragma unroll
  for (int i = 0; i < 4; ++i)
#pragma unroll
    for (int j = 0; j < 2; ++j) acc[i][j] = fz;

  const uint16_t* Ab_ = A + m0 * 1024;
  const uint16_t* Wb_ = W + n0 * 1024;
  stage64<4>(Ab_, 1024, sm, t);
  stage64<2>(Wb_, 1024, sm + 16384, t);

  for (int kt = 0; kt < 16; ++kt) {
    int cur = kt & 1;
    uint8_t* curb = sm + cur * 24576;
    asm volatile("s_waitcnt vmcnt(0)" ::: "memory");
    __syncthreads();
    if (kt + 1 < 16) {
      uint8_t* nb = sm + (cur ^ 1) * 24576;
      stage64<4>(Ab_ + (kt + 1) * 64, 1024, nb, t);
      stage64<2>(Wb_ + (kt + 1) * 64, 1024, nb + 16384, t);
    }
#pragma unroll
    for (int ks = 0; ks < 2; ++ks) {
      bf16x8 a[4], b[2];
#pragma unroll
      for (int i = 0; i < 4; ++i)
        a[i] = ld_frag(curb, wr + i * 16 + (l & 15), ks * 4 + (l >> 4));
#pragma unroll
      for (int j = 0; j < 2; ++j)
        b[j] = ld_frag(curb + 16384, wc + j * 16 + (l & 15), ks * 4 + (l >> 4));
#pragma unroll
      for (int i = 0; i < 4; ++i)
#pragma unroll
        for (int j = 0; j < 2; ++j)
          acc[i][j] = __builtin_amdgcn_mfma_f32_16x16x32_bf16(a[i], b[j], acc[i][j], 0, 0, 0);
    }
  }
#pragma unroll
  for (int j = 0; j < 2; ++j) {
    int e = n0 + wc + j * 16 + (l & 15);
    float bv = bias[e];
#pragma unroll
    for (int i = 0; i < 4; ++i) {
      int mb = m0 + wr + i * 16 + ((l >> 4) << 2);
#pragma unroll
      for (int r = 0; r < 4; ++r) {
        int m = mb + r;
        out[m * 1024 + e] = acc[i][j][r] + bv;
      }
    }
  }
}

// ---------------- Flash attention (causal): 64 q-rows per wave ----------------
// Grid 512 = 16 supertiles x 32 bh, 256 threads (4 waves), 2 blocks/CU.
// Block = one 128-q-row supertile st. Group g (waves {0,1} / {2,3}) consumes kv
// half [g*rounds, (g+1)*rounds) on its OWN dbuf LDS stream; wave wg owns 64 q
// rows (2 q-blocks of 32). Each K/V fragment LDS read feeds TWO MFMAs (qb=0,1)
// -> per-q LDS traffic halved vs 32q/wave (LDS pipe was the measured wall).
// Fixed-reference softmax (P = exp2(s)); 2-way kv merge = plain sums.
__global__ __launch_bounds__(256) void attn(const uint16_t* __restrict__ Qb,
                                            const uint16_t* __restrict__ Kb,
                                            const uint16_t* __restrict__ Vt,
                                            uint16_t* __restrict__ Ab,
                                            const int* __restrict__ maskp) {
  __shared__ uint8_t smem[65536];      // 2 groups x 2 buffers x (K 8KB + V 8KB)
  int t = threadIdx.x, l = t & 63, w = t >> 6;   // w 0..3
  int hi = l >> 5, ql = l & 31;
  int g = w >> 1, wg = w & 1;          // kv-half group, wave-in-group
  int tl = t & 127;                    // group-local thread id (2 waves)
  // XCD bh-affinity: did%8 = XCD; 4 bh per XCD; heavy st first (r18 mapping).
  int did = (int)blockIdx.x;
  int xcd = did & 7, idx = did >> 3;   // idx 0..63
  int st = 15 - (idx >> 2);            // supertile, heavy first
  int bh = xcd * 4 + (idx & 3);
  bool causal = (*maskp != 0);
  int rounds = causal ? (st + 1) : 16;
  int tile0 = g * rounds;              // my group's first kv tile
  int q0w = st * 128 + wg * 64;        // wave's q base (64 rows)
  int bb = bh >> 4, h = bh & 15;

  const uint16_t* KpB = Kb + ((size_t)bh << 17);   // [2048][64]
  const uint16_t* VpB = Vt + ((size_t)bh << 17);   // [64][2048] col-permuted
  uint8_t* gbuf = smem + (g << 15);    // my group's 32KB stream region

  // Q fragments (B-operand): qf[qb][ks] = Q[q0w + qb*32 + ql][ks*16 + hi*8 ..]
  bf16x8 qf[2][4];
#pragma unroll
  for (int qb = 0; qb < 2; ++qb) {
    const uint16_t* Qp = Qb + (((size_t)(bh * 2048 + q0w + qb * 32 + ql)) << 6) + hi * 8;
#pragma unroll
    for (int ks = 0; ks < 4; ++ks) qf[qb][ks] = *(const bf16x8*)(Qp + ks * 16);
  }

  f32x16 acc[2][2];                    // [qb][n]
#pragma unroll
  for (int qb = 0; qb < 2; ++qb)
#pragma unroll
    for (int n = 0; n < 2; ++n)
#pragma unroll
      for (int r = 0; r < 16; ++r) acc[qb][n][r] = 0.f;
  float lsum0 = 0.f, lsum1 = 0.f;

  // prologue: stage my group's tile0 into buffer 0 (128 threads x 4 issues/buf)
  stage64<4, 128>(KpB + ((size_t)tile0 << 12), 64, gbuf, tl);
  stage64<4, 128>(VpB + tile0 * 64, 2048, gbuf + 8192, tl);

  for (int rr = 0; rr < rounds; ++rr) {
    int tt = tile0 + rr;
    int cur = rr & 1;
    asm volatile("s_waitcnt vmcnt(0)" ::: "memory");   // my DMA landed
    __syncthreads();                                    // all landed; other bufs free
    if (rr + 1 < rounds) {                              // async prefetch (0 VGPR)
      uint8_t* nb = gbuf + ((cur ^ 1) << 14);
      stage64<4, 128>(KpB + ((size_t)(tt + 1) << 12), 64, nb, tl);
      stage64<4, 128>(VpB + (tt + 1) * 64, 2048, nb + 8192, tl);
    }
    if (causal && tt * 64 > q0w + 63) continue;        // fully masked for my 64 rows

    const uint8_t* Ks = gbuf + (cur << 14);
    const uint8_t* Vs = Ks + 8192;
    int qrel0 = q0w + ql - tt * 64;                    // qb=0 lane q rel to tile

#pragma unroll
    for (int f = 0; f < 2; ++f) {
      // ---- QK^T for kv rows [f*32, f*32+32): each kf read feeds both q-blocks ----
      f32x16 sc0, sc1;
#pragma unroll
      for (int r = 0; r < 16; ++r) { sc0[r] = 0.f; sc1[r] = 0.f; }
      __builtin_amdgcn_s_setprio(1);
#pragma unroll
      for (int ks = 0; ks < 4; ++ks) {
        bf16x8 kfr = ld_frag(Ks, f * 32 + ql, ks * 2 + hi);
        sc0 = __builtin_amdgcn_mfma_f32_32x32x16_bf16(kfr, qf[0][ks], sc0, 0, 0, 0);
        sc1 = __builtin_amdgcn_mfma_f32_32x32x16_bf16(kfr, qf[1][ks], sc1, 0, 0, 0);
      }
      __builtin_amdgcn_s_setprio(0);

      // ---- mask + exp (fixed-reference softmax) ----
      bool nm0 = (!causal) || (tt * 64 + f * 32 + 31 <= q0w);
      bool nm1 = (!causal) || (tt * 64 + f * 32 + 31 <= q0w + 32);
      float rsa = 0.f, rsb = 0.f;
#pragma unroll
      for (int r = 0; r < 16; ++r) {
        int kvr = f * 32 + (r & 3) + 8 * (r >> 2) + 4 * hi;
        float v0 = sc0[r];
        if (!nm0) v0 = (kvr <= qrel0) ? v0 : -1e30f;
        float e0 = fexp2(v0);
        sc0[r] = e0;
        rsa += e0;
        float v1 = sc1[r];
        if (!nm1) v1 = (kvr <= qrel0 + 32) ? v1 : -1e30f;
        float e1 = fexp2(v1);
        sc1[r] = e1;
        rsb += e1;
      }
      lsum0 += rsa;
      lsum1 += rsb;

      // ---- PV: each vf read feeds both q-blocks ----
      __builtin_amdgcn_s_setprio(1);
#pragma unroll
      for (int k2 = 0; k2 < 2; ++k2) {
        int a8 = k2 * 8;
        u32x4 w0 = {cvtpk(sc0[a8 + 0], sc0[a8 + 1]), cvtpk(sc0[a8 + 2], sc0[a8 + 3]),
                    cvtpk(sc0[a8 + 4], sc0[a8 + 5]), cvtpk(sc0[a8 + 6], sc0[a8 + 7])};
        u32x4 w1 = {cvtpk(sc1[a8 + 0], sc1[a8 + 1]), cvtpk(sc1[a8 + 2], sc1[a8 + 3]),
                    cvtpk(sc1[a8 + 4], sc1[a8 + 5]), cvtpk(sc1[a8 + 6], sc1[a8 + 7])};
        bf16x8 a0 = __builtin_bit_cast(bf16x8, w0);
        bf16x8 a1 = __builtin_bit_cast(bf16x8, w1);
#pragma unroll
        for (int n = 0; n < 2; ++n) {
          bf16x8 vfr = ld_frag(Vs, n * 32 + ql, (f * 2 + k2) * 2 + hi);
          acc[0][n] = __builtin_amdgcn_mfma_f32_32x32x16_bf16(a0, vfr, acc[0][n], 0, 0, 0);
          acc[1][n] = __builtin_amdgcn_mfma_f32_32x32x16_bf16(a1, vfr, acc[1][n], 0, 0, 0);
        }
      }
      __builtin_amdgcn_s_setprio(0);
    }
  }

  // ---- 2-way kv-half merge (plain sums; LDS aliases stream buffers) ----
  __syncthreads();                     // all loops done; safe to alias LDS
  lsum0 += __shfl_xor(lsum0, 32);
  lsum1 += __shfl_xor(lsum1, 32);
  float (*oaccS)[64][65] = (float(*)[64][65])smem;          // [wg][lane][64+pad]
  float (*lsumS)[64][2]  = (float(*)[64][2])(smem + 34816); // [wg][lane][qb]
  if (g == 1) {
#pragma unroll
    for (int qb = 0; qb < 2; ++qb)
#pragma unroll
      for (int n = 0; n < 2; ++n)
#pragma unroll
        for (int r = 0; r < 16; ++r)
          oaccS[wg][l][qb * 32 + n * 16 + r] = acc[qb][n][r];
    lsumS[wg][l][0] = lsum0;
    lsumS[wg][l][1] = lsum1;
  }
  __syncthreads();
  if (g == 0) {
#pragma unroll
    for (int qb = 0; qb < 2; ++qb)
#pragma unroll
      for (int n = 0; n < 2; ++n)
#pragma unroll
        for (int r = 0; r < 16; ++r)
          acc[qb][n][r] += oaccS[wg][l][qb * 32 + n * 16 + r];
    lsum0 += lsumS[wg][l][0];
    lsum1 += lsumS[wg][l][1];
#pragma unroll
    for (int qb = 0; qb < 2; ++qb) {
      float ls = qb ? lsum1 : lsum0;
#pragma unroll
      for (int r = 0; r < 16; ++r) {
        int crow = (r & 3) + 8 * (r >> 2) + 4 * hi;
        float L = __shfl(ls, crow);
        float inv = 1.0f / L;
        int qg = q0w + qb * 32 + crow;
#pragma unroll
        for (int n = 0; n < 2; ++n)
          Ab[(((size_t)(bb * 2048 + qg)) << 10) + h * 64 + n * 32 + ql] =
              f2b(acc[qb][n][r] * inv);
      }
    }
  }
}

extern "C" void kernel_launch(void* const* d_in, const int* in_sizes, int n_in,
                              void* d_out, int out_size, void* d_ws, size_t ws_size,
                              hipStream_t stream) {
  const float* x     = (const float*)d_in[0];
  const float* w_in  = (const float*)d_in[1];
  const float* b_in  = (const float*)d_in[2];
  const float* w_out = (const float*)d_in[3];
  const float* b_out = (const float*)d_in[4];
  const int*   mask  = (const int*)d_in[5];
  float* out = (float*)d_out;

  uint8_t* ws = (uint8_t*)d_ws;
  uint16_t* xb  = (uint16_t*)(ws);                  // 8 MB  x bf16 [4096][1024]
  uint16_t* wib = (uint16_t*)(ws + (8u << 20));     // 6 MB  w_in bf16 [3072][1024]
  uint16_t* wob = (uint16_t*)(ws + (14u << 20));    // 2 MB  w_out bf16 [1024][1024]
  uint16_t* Qb  = (uint16_t*)(ws + (16u << 20));    // 8 MB  (B,H,S,DH) pre-scaled
  uint16_t* Kb  = (uint16_t*)(ws + (24u << 20));    // 8 MB  (B,H,S,DH)
  uint16_t* Vt  = (uint16_t*)(ws + (32u << 20));    // 8 MB  (B,H,DH,S) col-permuted
  uint16_t* Ab  = (uint16_t*)(ws + (40u << 20));    // 8 MB  att (B,S,D) bf16

  cvt3<<<8192, 256, 0, stream>>>(x, w_in, w_out, xb, wib, wob);
  gemm_qkv<<<dim3(48, 32), 256, 0, stream>>>(xb, wib, b_in, Qb, Kb, Vt);
  attn<<<512, 256, 0, stream>>>(Qb, Kb, Vt, Ab, mask);
  gemm_out<<<dim3(16, 32), 256, 0, stream>>>(Ab, wob, b_out, out);
}

// Round 23
// 117.176 us; speedup vs baseline: 1.0357x; 1.0357x over previous
//
#include <hip/hip_runtime.h>
#include <hip/hip_bf16.h>
#include <stdint.h>

// B=2, S=2048, D=1024, H=16, DH=64. Causal self-attention block, bf16 MFMA pipeline.

typedef __attribute__((ext_vector_type(8))) short bf16x8;   // 8 bf16 = 16B (A/B frag)
typedef __attribute__((ext_vector_type(4))) float f32x4;    // C/D frag 16x16
typedef __attribute__((ext_vector_type(16))) float f32x16;  // C/D frag 32x32
typedef __attribute__((ext_vector_type(4))) unsigned int u32x4;

typedef const __attribute__((address_space(1))) uint32_t* gp1_t;
typedef __attribute__((address_space(3))) uint32_t* lp3_t;

// v_cvt_pk_bf16_f32: dst.lo = bf16(lo), dst.hi = bf16(hi)  (RNE, 1 VALU op)
static __device__ __forceinline__ uint32_t cvtpk(float lo, float hi) {
  uint32_t r;
  asm("v_cvt_pk_bf16_f32 %0, %1, %2" : "=v"(r) : "v"(lo), "v"(hi));
  return r;
}
// single-value f32->bf16 in ONE instruction (low half of cvt_pk)
static __device__ __forceinline__ uint16_t f2b(float x) {
  return (uint16_t)cvtpk(x, x);
}
// raw hardware exp2 (1 VALU op; underflow flushes to 0 — fine for masked -1e30)
static __device__ __forceinline__ float fexp2(float x) {
  float r;
  asm("v_exp_f32 %0, %1" : "=v"(r) : "v"(x));
  return r;
}

// Stage rows x 64 bf16 (128B = 8 chunks of 16B) tile into LDS, async DMA.
// THR participating threads; covers ISSUES*THR chunks (rows = ISSUES*THR/8).
template <int ISSUES, int THR = 256>
static __device__ __forceinline__ void stage64(const uint16_t* __restrict__ g, int gstride,
                                               uint8_t* lds, int t) {
#pragma unroll
  for (int i = 0; i < ISSUES; ++i) {
    int p = i * THR + t;          // 16B-chunk index
    int row = p >> 3, c = p & 7;
    const uint16_t* src = g + row * gstride + ((c ^ (row & 7)) << 3);
    __builtin_amdgcn_global_load_lds((gp1_t)src, (lp3_t)(lds + (p & ~63) * 16), 16, 0, 0);
  }
}

// Read a 16B fragment from a swizzled [R][64] bf16 tile: 8 bf16 at (row, chunk*8).
static __device__ __forceinline__ bf16x8 ld_frag(const uint8_t* lds, int row, int chunk) {
  return *(const bf16x8*)(lds + row * 128 + (((chunk) ^ (row & 7)) << 4));
}

// ---------------- f32 -> bf16 convert (x, w_in, w_out fused in one launch) ----------------
__global__ __launch_bounds__(256) void cvt3(const float* __restrict__ a,
                                            const float* __restrict__ b,
                                            const float* __restrict__ c,
                                            uint16_t* __restrict__ oa,
                                            uint16_t* __restrict__ ob,
                                            uint16_t* __restrict__ oc) {
  int i = blockIdx.x * 256 + threadIdx.x;   // in float4 units
  const float* src;
  uint16_t* dst;
  int j;
  if (i < 1048576)      { src = a; dst = oa; j = i; }
  else if (i < 1835008) { src = b; dst = ob; j = i - 1048576; }
  else                  { src = c; dst = oc; j = i - 1835008; }
  float4 v = ((const float4*)src)[j];
  uint2 o;
  o.x = cvtpk(v.x, v.y);
  o.y = cvtpk(v.z, v.w);
  ((uint2*)dst)[j] = o;
}

// ---------------- GEMM1: qkv = x @ w_in^T + b_in ----------------
// BM=128, BN=64 (one head per block -> section-uniform epilogue), BK=64.
// Double-buffered LDS (24KB/buf, 48KB total -> 3 blocks/CU resident), ONE barrier
// per K-step (r18-proven). XCD swizzle: each XCD owns 4 contiguous by-rows.
__global__ __launch_bounds__(256) void gemm_qkv(const uint16_t* __restrict__ A,
                                                const uint16_t* __restrict__ W,
                                                const float* __restrict__ bias,
                                                uint16_t* __restrict__ Qb,
                                                uint16_t* __restrict__ Kb,
                                                uint16_t* __restrict__ Vt) {
  __shared__ uint8_t smraw[49152];     // 2 x (A 16KB + B 8KB); epilogue ot aliases
  int t = threadIdx.x, l = t & 63, w = t >> 6;
  // XCD-bijective remap (nwg=1536, %8==0): each XCD -> 4 contiguous by rows.
  int bid = (int)blockIdx.x + 48 * (int)blockIdx.y;
  int virt = (bid & 7) * 192 + (bid >> 3);
  int bx = virt % 48, by = virt / 48;
  int m0 = by * 128, n0 = bx * 64;
  int wr = (w >> 1) * 64, wc = (w & 1) * 32;
  const f32x4 fz = {0.f, 0.f, 0.f, 0.f};
  f32x4 acc[4][2];
#pragma unroll
  for (int i = 0; i < 4; ++i)
#pragma unroll
    for (int j = 0; j < 2; ++j) acc[i][j] = fz;

  const uint16_t* Ab_ = A + m0 * 1024;
  const uint16_t* Wb_ = W + n0 * 1024;
  stage64<4>(Ab_, 1024, smraw, t);
  stage64<2>(Wb_, 1024, smraw + 16384, t);

  for (int kt = 0; kt < 16; ++kt) {
    int cur = kt & 1;
    uint8_t* curb = smraw + cur * 24576;
    asm volatile("s_waitcnt vmcnt(0)" ::: "memory");  // my DMA landed
    __syncthreads();                                   // all landed; other buf free
    if (kt + 1 < 16) {
      uint8_t* nb = smraw + (cur ^ 1) * 24576;
      stage64<4>(Ab_ + (kt + 1) * 64, 1024, nb, t);
      stage64<2>(Wb_ + (kt + 1) * 64, 1024, nb + 16384, t);
    }
#pragma unroll
    for (int ks = 0; ks < 2; ++ks) {
      bf16x8 a[4], b[2];
#pragma unroll
      for (int i = 0; i < 4; ++i)
        a[i] = ld_frag(curb, wr + i * 16 + (l & 15), ks * 4 + (l >> 4));
#pragma unroll
      for (int j = 0; j < 2; ++j)
        b[j] = ld_frag(curb + 16384, wc + j * 16 + (l & 15), ks * 4 + (l >> 4));
#pragma unroll
      for (int i = 0; i < 4; ++i)
#pragma unroll
        for (int j = 0; j < 2; ++j)
          acc[i][j] = __builtin_amdgcn_mfma_f32_16x16x32_bf16(a[i], b[j], acc[i][j], 0, 0, 0);
    }
  }

  // ---- epilogue: acc -> LDS ----
  __syncthreads();                       // staging dead; reuse as ot
  uint16_t* ot = (uint16_t*)smraw;       // Q/K: [row][72]; V: [col][136] transposed
  const float CSQ = 0.18033688011112042f;  // 0.125 * log2(e)
  int sec = n0 >> 10;                    // block-uniform: 0=Q 1=K 2=V
#pragma unroll
  for (int j = 0; j < 2; ++j) {
    int col = wc + j * 16 + (l & 15);    // 0..63
    float bv = bias[n0 + col];
#pragma unroll
    for (int i = 0; i < 4; ++i) {
      int rb = wr + i * 16 + ((l >> 4) << 2);
#pragma unroll
      for (int r = 0; r < 4; ++r) {
        int row = rb + r;                // 0..127
        float v = acc[i][j][r] + bv;
        if (sec == 0) v *= CSQ;
        if (sec == 2) {
          int rowp = (row & ~12) | ((row & 4) << 1) | ((row & 8) >> 1);  // s bits 2<->3
          ot[col * 136 + rowp] = f2b(v); // transposed for V
        } else {
          ot[row * 72 + col] = f2b(v);
        }
      }
    }
  }
  __syncthreads();

  // ---- coalesced stores (block = one head) ----
  int bb0 = m0 >> 11, sbase = m0 & 2047;
  int h = (n0 & 1023) >> 6;
  if (sec < 2) {
    uint16_t* dst0 = (sec == 0) ? Qb : Kb;
    int s_loc = t >> 1, half = t & 1;
    const uint16_t* src = ot + s_loc * 72 + half * 32;
    uint16_t* dst = dst0 + (((size_t)((bb0 * 16 + h) * 2048 + sbase + s_loc)) << 6) + half * 32;
#pragma unroll
    for (int c = 0; c < 4; ++c)
      *(u32x4*)(dst + c * 8) = *(const u32x4*)(src + c * 8);
  } else {
    int dh = t >> 2, qr = t & 3;
    const uint16_t* src = ot + dh * 136 + qr * 32;
    uint16_t* dst = Vt + ((size_t)((bb0 * 16 + h) * 64 + dh)) * 2048 + sbase + qr * 32;
#pragma unroll
    for (int c = 0; c < 4; ++c)
      *(u32x4*)(dst + c * 8) = *(const u32x4*)(src + c * 8);
  }
}

// ---------------- GEMM2: out = att @ w_out^T + b_out (f32 out) ----------------
// BM=64, BN=64, BK=64 dbuf (32KB LDS) -> grid 1024 = 4 blocks/CU resident
// (was 512 @ 2/CU): doubles waves/SIMD for the same 1-barrier dbuf loop.
__global__ __launch_bounds__(256) void gemm_out(const uint16_t* __restrict__ A,
                                                const uint16_t* __restrict__ W,
                                                const float* __restrict__ bias,
                                                float* __restrict__ out) {
  __shared__ uint8_t sm[32768];          // 2 x (A 8KB + B 8KB)
  int t = threadIdx.x, l = t & 63, w = t >> 6;
  int bid = (int)blockIdx.x + 16 * (int)blockIdx.y;   // nwg = 1024
  int virt = (bid & 7) * 128 + (bid >> 3);            // XCD-bijective
  int bx = virt % 16, by = virt / 16;
  int m0 = by * 64, n0 = bx * 64;
  int wr = (w >> 1) * 32, wc = (w & 1) * 32;
  const f32x4 fz = {0.f, 0.f, 0.f, 0.f};
  f32x4 acc[2][2];
#pragma unroll
  for (int i = 0; i < 2; ++i)
#pragma unroll
    for (int j = 0; j < 2; ++j) acc[i][j] = fz;

  const uint16_t* Ab_ = A + m0 * 1024;
  const uint16_t* Wb_ = W + n0 * 1024;
  stage64<2>(Ab_, 1024, sm, t);
  stage64<2>(Wb_, 1024, sm + 8192, t);

  for (int kt = 0; kt < 16; ++kt) {
    int cur = kt & 1;
    uint8_t* curb = sm + cur * 16384;
    asm volatile("s_waitcnt vmcnt(0)" ::: "memory");
    __syncthreads();
    if (kt + 1 < 16) {
      uint8_t* nb = sm + (cur ^ 1) * 16384;
      stage64<2>(Ab_ + (kt + 1) * 64, 1024, nb, t);
      stage64<2>(Wb_ + (kt + 1) * 64, 1024, nb + 8192, t);
    }
#pragma unroll
    for (int ks = 0; ks < 2; ++ks) {
      bf16x8 a[2], b[2];
#pragma unroll
      for (int i = 0; i < 2; ++i)
        a[i] = ld_frag(curb, wr + i * 16 + (l & 15), ks * 4 + (l >> 4));
#pragma unroll
      for (int j = 0; j < 2; ++j)
        b[j] = ld_frag(curb + 8192, wc + j * 16 + (l & 15), ks * 4 + (l >> 4));
#pragma unroll
      for (int i = 0; i < 2; ++i)
#pragma unroll
        for (int j = 0; j < 2; ++j)
          acc[i][j] = __builtin_amdgcn_mfma_f32_16x16x32_bf16(a[i], b[j], acc[i][j], 0, 0, 0);
    }
  }
#pragma unroll
  for (int j = 0; j < 2; ++j) {
    int e = n0 + wc + j * 16 + (l & 15);
    float bv = bias[e];
#pragma unroll
    for (int i = 0; i < 2; ++i) {
      int mb = m0 + wr + i * 16 + ((l >> 4) << 2);
#pragma unroll
      for (int r = 0; r < 4; ++r) {
        int m = mb + r;
        out[m * 1024 + e] = acc[i][j][r] + bv;
      }
    }
  }
}

// ---------------- Flash attention (causal): kv-halved dual-stream blocks ----------------
// r21-proven version (32 q-rows/wave, VGPR ~96). Grid 512 = 16 supertiles x 32 bh,
// 512 threads (8 waves), 2 blocks/CU. Group A (waves 0-3) consumes kv tiles
// [0, st+1); group B (waves 4-7) consumes [st+1, 2st+2) on its OWN dbuf stream.
// Fixed-reference softmax (P = exp2(s)); 2-way kv merge = plain sums.
__global__ __launch_bounds__(512) void attn(const uint16_t* __restrict__ Qb,
                                            const uint16_t* __restrict__ Kb,
                                            const uint16_t* __restrict__ Vt,
                                            uint16_t* __restrict__ Ab,
                                            const int* __restrict__ maskp) {
  __shared__ uint8_t smem[65536];      // 2 groups x 2 buffers x (K 8KB + V 8KB)
  int t = threadIdx.x, l = t & 63, w = t >> 6;   // w 0..7
  int hi = l >> 5, ql = l & 31;
  int g = w >> 2, wg = w & 3;          // kv-half group, wave-in-group
  int tl = t & 255;                    // group-local thread id
  // XCD bh-affinity: did%8 = XCD; 4 bh per XCD; heavy st first (r18 mapping).
  int did = (int)blockIdx.x;
  int xcd = did & 7, idx = did >> 3;   // idx 0..63
  int st = 15 - (idx >> 2);            // supertile, heavy first
  int bh = xcd * 4 + (idx & 3);
  bool causal = (*maskp != 0);
  int rounds = causal ? (st + 1) : 16;
  int tile0 = g * rounds;              // my group's first kv tile
  int q0w = st * 128 + wg * 32;        // wave's q base
  int q = q0w + ql;
  int bb = bh >> 4, h = bh & 15;

  const uint16_t* KpB = Kb + ((size_t)bh << 17);   // [2048][64]
  const uint16_t* VpB = Vt + ((size_t)bh << 17);   // [64][2048] col-permuted
  uint8_t* gbuf = smem + (g << 15);    // my group's 32KB stream region

  // Q fragments (B-operand): Q[q][dh = ks*16 + hi*8 + j], pre-scaled by CSQ
  bf16x8 qf[4];
  const uint16_t* Qp = Qb + (((size_t)bh * 2048 + q) << 6) + hi * 8;
#pragma unroll
  for (int ks = 0; ks < 4; ++ks) qf[ks] = *(const bf16x8*)(Qp + ks * 16);

  f32x16 acco[2];
#pragma unroll
  for (int r = 0; r < 16; ++r) { acco[0][r] = 0.f; acco[1][r] = 0.f; }
  float lsum = 0.f;

  // prologue: stage my group's tile0 into buffer 0 (256 threads x 2 issues/buf)
  stage64<2>(KpB + ((size_t)tile0 << 12), 64, gbuf, tl);
  stage64<2>(VpB + tile0 * 64, 2048, gbuf + 8192, tl);

  for (int rr = 0; rr < rounds; ++rr) {
    int tt = tile0 + rr;
    int cur = rr & 1;
    asm volatile("s_waitcnt vmcnt(0)" ::: "memory");   // my DMA landed
    __syncthreads();                                    // all landed; other bufs free
    if (rr + 1 < rounds) {                              // async prefetch (0 VGPR)
      uint8_t* nb = gbuf + ((cur ^ 1) << 14);
      stage64<2>(KpB + ((size_t)(tt + 1) << 12), 64, nb, tl);
      stage64<2>(VpB + (tt + 1) * 64, 2048, nb + 8192, tl);
    }
    if (causal && tt * 64 > q0w + 31) continue;        // fully masked for my rows

    const uint8_t* Ks = gbuf + (cur << 14);
    const uint8_t* Vs = Ks + 8192;
    bf16x8 kf[2][4], vf[2][4];
#pragma unroll
    for (int ks = 0; ks < 4; ++ks) {
      kf[0][ks] = ld_frag(Ks, ql,      ks * 2 + hi);
      kf[1][ks] = ld_frag(Ks, 32 + ql, ks * 2 + hi);
      vf[0][ks] = ld_frag(Vs, ql,      ks * 2 + hi);
      vf[1][ks] = ld_frag(Vs, 32 + ql, ks * 2 + hi);
    }

    // ---- QK^T: sc[f][r] = S[kv = tt*64 + f*32 + crow(r,hi)][q] (log2 units) ----
    f32x16 sc[2];
#pragma unroll
    for (int r = 0; r < 16; ++r) { sc[0][r] = 0.f; sc[1][r] = 0.f; }
    __builtin_amdgcn_s_setprio(1);
#pragma unroll
    for (int ks = 0; ks < 4; ++ks)
      sc[0] = __builtin_amdgcn_mfma_f32_32x32x16_bf16(kf[0][ks], qf[ks], sc[0], 0, 0, 0);
#pragma unroll
    for (int ks = 0; ks < 4; ++ks)
      sc[1] = __builtin_amdgcn_mfma_f32_32x32x16_bf16(kf[1][ks], qf[ks], sc[1], 0, 0, 0);
    __builtin_amdgcn_s_setprio(0);

    bool nomask = (!causal) || (tt * 64 + 63 <= q0w);
    int qrel = q - tt * 64;
    float rs0 = 0.f, rs1 = 0.f, rs2 = 0.f, rs3 = 0.f;

    // ---- exp half f=0 (overlaps QK f=1 MFMA latency) ----
#pragma unroll
    for (int r = 0; r < 16; ++r) {
      float v = sc[0][r];
      if (!nomask) {
        int kv = (r & 3) + 8 * (r >> 2) + 4 * hi;
        v = (kv <= qrel) ? v : -1e30f;
      }
      float e = fexp2(v);
      sc[0][r] = e;
      if (r & 1) rs1 += e; else rs0 += e;
    }

    // ---- PV ks=0,1 (uses sc[0]) ----
    __builtin_amdgcn_s_setprio(1);
#pragma unroll
    for (int ks = 0; ks < 2; ++ks) {
      int a8 = ks * 8;
      u32x4 wv = {cvtpk(sc[0][a8 + 0], sc[0][a8 + 1]),
                  cvtpk(sc[0][a8 + 2], sc[0][a8 + 3]),
                  cvtpk(sc[0][a8 + 4], sc[0][a8 + 5]),
                  cvtpk(sc[0][a8 + 6], sc[0][a8 + 7])};
      bf16x8 af = __builtin_bit_cast(bf16x8, wv);
      acco[0] = __builtin_amdgcn_mfma_f32_32x32x16_bf16(af, vf[0][ks], acco[0], 0, 0, 0);
      acco[1] = __builtin_amdgcn_mfma_f32_32x32x16_bf16(af, vf[1][ks], acco[1], 0, 0, 0);
    }
    __builtin_amdgcn_s_setprio(0);

    // ---- exp half f=1 ----
#pragma unroll
    for (int r = 0; r < 16; ++r) {
      float v = sc[1][r];
      if (!nomask) {
        int kv = 32 + (r & 3) + 8 * (r >> 2) + 4 * hi;
        v = (kv <= qrel) ? v : -1e30f;
      }
      float e = fexp2(v);
      sc[1][r] = e;
      if (r & 1) rs3 += e; else rs2 += e;
    }

    // ---- PV ks=2,3 (uses sc[1]) ----
    __builtin_amdgcn_s_setprio(1);
#pragma unroll
    for (int ks = 0; ks < 2; ++ks) {
      int a8 = ks * 8;
      u32x4 wv = {cvtpk(sc[1][a8 + 0], sc[1][a8 + 1]),
                  cvtpk(sc[1][a8 + 2], sc[1][a8 + 3]),
                  cvtpk(sc[1][a8 + 4], sc[1][a8 + 5]),
                  cvtpk(sc[1][a8 + 6], sc[1][a8 + 7])};
      bf16x8 af = __builtin_bit_cast(bf16x8, wv);
      acco[0] = __builtin_amdgcn_mfma_f32_32x32x16_bf16(af, vf[0][ks + 2], acco[0], 0, 0, 0);
      acco[1] = __builtin_amdgcn_mfma_f32_32x32x16_bf16(af, vf[1][ks + 2], acco[1], 0, 0, 0);
    }
    __builtin_amdgcn_s_setprio(0);

    lsum += (rs0 + rs1) + (rs2 + rs3);
  }

  // ---- 2-way kv-half merge (plain sums; LDS aliases stream buffers) ----
  __syncthreads();                     // all loops done; safe to alias LDS
  lsum += __shfl_xor(lsum, 32);        // lanes ql / ql+32 both hold full row-sum
  float (*oaccS)[64][33] = (float(*)[64][33])smem;          // [4][64][33]
  float (*lsumS)[64]     = (float(*)[64])(smem + 33792);    // [4][64]
  if (g == 1) {
#pragma unroll
    for (int r = 0; r < 16; ++r) {
      oaccS[wg][l][r] = acco[0][r];
      oaccS[wg][l][16 + r] = acco[1][r];
    }
    lsumS[wg][l] = lsum;
  }
  __syncthreads();
  if (g == 0) {
#pragma unroll
    for (int r = 0; r < 16; ++r) {
      acco[0][r] += oaccS[wg][l][r];
      acco[1][r] += oaccS[wg][l][16 + r];
    }
    lsum += lsumS[wg][l];
#pragma unroll
    for (int r = 0; r < 16; ++r) {
      int crow = (r & 3) + 8 * (r >> 2) + 4 * hi;
      float L = __shfl(lsum, crow);
      float inv = 1.0f / L;
      int qg = q0w + crow;
#pragma unroll
      for (int n = 0; n < 2; ++n)
        Ab[(((size_t)(bb * 2048 + qg)) << 10) + h * 64 + n * 32 + ql] = f2b(acco[n][r] * inv);
    }
  }
}

extern "C" void kernel_launch(void* const* d_in, const int* in_sizes, int n_in,
                              void* d_out, int out_size, void* d_ws, size_t ws_size,
                              hipStream_t stream) {
  const float* x     = (const float*)d_in[0];
  const float* w_in  = (const float*)d_in[1];
  const float* b_in  = (const float*)d_in[2];
  const float* w_out = (const float*)d_in[3];
  const float* b_out = (const float*)d_in[4];
  const int*   mask  = (const int*)d_in[5];
  float* out = (float*)d_out;

  uint8_t* ws = (uint8_t*)d_ws;
  uint16_t* xb  = (uint16_t*)(ws);                  // 8 MB  x bf16 [4096][1024]
  uint16_t* wib = (uint16_t*)(ws + (8u << 20));     // 6 MB  w_in bf16 [3072][1024]
  uint16_t* wob = (uint16_t*)(ws + (14u << 20));    // 2 MB  w_out bf16 [1024][1024]
  uint16_t* Qb  = (uint16_t*)(ws + (16u << 20));    // 8 MB  (B,H,S,DH) pre-scaled
  uint16_t* Kb  = (uint16_t*)(ws + (24u << 20));    // 8 MB  (B,H,S,DH)
  uint16_t* Vt  = (uint16_t*)(ws + (32u << 20));    // 8 MB  (B,H,DH,S) col-permuted
  uint16_t* Ab  = (uint16_t*)(ws + (40u << 20));    // 8 MB  att (B,S,D) bf16

  cvt3<<<8192, 256, 0, stream>>>(x, w_in, w_out, xb, wib, wob);
  gemm_qkv<<<dim3(48, 32), 256, 0, stream>>>(xb, wib, b_in, Qb, Kb, Vt);
  attn<<<512, 512, 0, stream>>>(Qb, Kb, Vt, Ab, mask);
  gemm_out<<<dim3(16, 64), 256, 0, stream>>>(Ab, wob, b_out, out);
}

// Round 24
// 112.248 us; speedup vs baseline: 1.0812x; 1.0439x over previous
//
#include <hip/hip_runtime.h>
#include <hip/hip_bf16.h>
#include <stdint.h>

// B=2, S=2048, D=1024, H=16, DH=64. Causal self-attention block, bf16 MFMA pipeline.

typedef __attribute__((ext_vector_type(8))) short bf16x8;   // 8 bf16 = 16B (A/B frag)
typedef __attribute__((ext_vector_type(4))) float f32x4;    // C/D frag 16x16
typedef __attribute__((ext_vector_type(16))) float f32x16;  // C/D frag 32x32
typedef __attribute__((ext_vector_type(4))) unsigned int u32x4;

typedef const __attribute__((address_space(1))) uint32_t* gp1_t;
typedef __attribute__((address_space(3))) uint32_t* lp3_t;

// v_cvt_pk_bf16_f32: dst.lo = bf16(lo), dst.hi = bf16(hi)  (RNE, 1 VALU op)
static __device__ __forceinline__ uint32_t cvtpk(float lo, float hi) {
  uint32_t r;
  asm("v_cvt_pk_bf16_f32 %0, %1, %2" : "=v"(r) : "v"(lo), "v"(hi));
  return r;
}
// single-value f32->bf16 in ONE instruction (low half of cvt_pk)
static __device__ __forceinline__ uint16_t f2b(float x) {
  return (uint16_t)cvtpk(x, x);
}
// raw hardware exp2 (1 VALU op; underflow flushes to 0 — fine for masked -1e30)
static __device__ __forceinline__ float fexp2(float x) {
  float r;
  asm("v_exp_f32 %0, %1" : "=v"(r) : "v"(x));
  return r;
}

// Stage rows x 64 bf16 (128B = 8 chunks of 16B) tile into LDS, async DMA.
template <int ISSUES, int THR = 256>
static __device__ __forceinline__ void stage64(const uint16_t* __restrict__ g, int gstride,
                                               uint8_t* lds, int t) {
#pragma unroll
  for (int i = 0; i < ISSUES; ++i) {
    int p = i * THR + t;          // 16B-chunk index
    int row = p >> 3, c = p & 7;
    const uint16_t* src = g + row * gstride + ((c ^ (row & 7)) << 3);
    __builtin_amdgcn_global_load_lds((gp1_t)src, (lp3_t)(lds + (p & ~63) * 16), 16, 0, 0);
  }
}

// Read a 16B fragment from a swizzled [R][64] bf16 tile: 8 bf16 at (row, chunk*8).
static __device__ __forceinline__ bf16x8 ld_frag(const uint8_t* lds, int row, int chunk) {
  return *(const bf16x8*)(lds + row * 128 + (((chunk) ^ (row & 7)) << 4));
}

// ---------------- f32 -> bf16 convert (x, w_in, w_out fused in one launch) ----------------
__global__ __launch_bounds__(256) void cvt3(const float* __restrict__ a,
                                            const float* __restrict__ b,
                                            const float* __restrict__ c,
                                            uint16_t* __restrict__ oa,
                                            uint16_t* __restrict__ ob,
                                            uint16_t* __restrict__ oc) {
  int i = blockIdx.x * 256 + threadIdx.x;   // in float4 units
  const float* src;
  uint16_t* dst;
  int j;
  if (i < 1048576)      { src = a; dst = oa; j = i; }
  else if (i < 1835008) { src = b; dst = ob; j = i - 1048576; }
  else                  { src = c; dst = oc; j = i - 1835008; }
  float4 v = ((const float4*)src)[j];
  uint2 o;
  o.x = cvtpk(v.x, v.y);
  o.y = cvtpk(v.z, v.w);
  ((uint2*)dst)[j] = o;
}

// ---------------- GEMM1: qkv = x @ w_in^T + b_in ----------------
// BM=128, BN=64 (one head per block -> section-uniform epilogue), BK=64.
// Double-buffered LDS (24KB/buf, 48KB total -> 3 blocks/CU resident), ONE barrier
// per K-step (r18-proven). XCD swizzle: each XCD owns 4 contiguous by-rows.
__global__ __launch_bounds__(256) void gemm_qkv(const uint16_t* __restrict__ A,
                                                const uint16_t* __restrict__ W,
                                                const float* __restrict__ bias,
                                                uint16_t* __restrict__ Qb,
                                                uint16_t* __restrict__ Kb,
                                                uint16_t* __restrict__ Vt) {
  __shared__ uint8_t smraw[49152];     // 2 x (A 16KB + B 8KB); epilogue ot aliases
  int t = threadIdx.x, l = t & 63, w = t >> 6;
  // XCD-bijective remap (nwg=1536, %8==0): each XCD -> 4 contiguous by rows.
  int bid = (int)blockIdx.x + 48 * (int)blockIdx.y;
  int virt = (bid & 7) * 192 + (bid >> 3);
  int bx = virt % 48, by = virt / 48;
  int m0 = by * 128, n0 = bx * 64;
  int wr = (w >> 1) * 64, wc = (w & 1) * 32;
  const f32x4 fz = {0.f, 0.f, 0.f, 0.f};
  f32x4 acc[4][2];
#pragma unroll
  for (int i = 0; i < 4; ++i)
#pragma unroll
    for (int j = 0; j < 2; ++j) acc[i][j] = fz;

  const uint16_t* Ab_ = A + m0 * 1024;
  const uint16_t* Wb_ = W + n0 * 1024;
  stage64<4>(Ab_, 1024, smraw, t);
  stage64<2>(Wb_, 1024, smraw + 16384, t);

  for (int kt = 0; kt < 16; ++kt) {
    int cur = kt & 1;
    uint8_t* curb = smraw + cur * 24576;
    asm volatile("s_waitcnt vmcnt(0)" ::: "memory");  // my DMA landed
    __syncthreads();                                   // all landed; other buf free
    if (kt + 1 < 16) {
      uint8_t* nb = smraw + (cur ^ 1) * 24576;
      stage64<4>(Ab_ + (kt + 1) * 64, 1024, nb, t);
      stage64<2>(Wb_ + (kt + 1) * 64, 1024, nb + 16384, t);
    }
#pragma unroll
    for (int ks = 0; ks < 2; ++ks) {
      bf16x8 a[4], b[2];
#pragma unroll
      for (int i = 0; i < 4; ++i)
        a[i] = ld_frag(curb, wr + i * 16 + (l & 15), ks * 4 + (l >> 4));
#pragma unroll
      for (int j = 0; j < 2; ++j)
        b[j] = ld_frag(curb + 16384, wc + j * 16 + (l & 15), ks * 4 + (l >> 4));
#pragma unroll
      for (int i = 0; i < 4; ++i)
#pragma unroll
        for (int j = 0; j < 2; ++j)
          acc[i][j] = __builtin_amdgcn_mfma_f32_16x16x32_bf16(a[i], b[j], acc[i][j], 0, 0, 0);
    }
  }

  // ---- epilogue: acc -> LDS ----
  __syncthreads();                       // staging dead; reuse as ot
  uint16_t* ot = (uint16_t*)smraw;       // Q/K: [row][72]; V: [col][136] transposed
  const float CSQ = 0.18033688011112042f;  // 0.125 * log2(e)
  int sec = n0 >> 10;                    // block-uniform: 0=Q 1=K 2=V
#pragma unroll
  for (int j = 0; j < 2; ++j) {
    int col = wc + j * 16 + (l & 15);    // 0..63
    float bv = bias[n0 + col];
#pragma unroll
    for (int i = 0; i < 4; ++i) {
      int rb = wr + i * 16 + ((l >> 4) << 2);
#pragma unroll
      for (int r = 0; r < 4; ++r) {
        int row = rb + r;                // 0..127
        float v = acc[i][j][r] + bv;
        if (sec == 0) v *= CSQ;
        if (sec == 2) {
          int rowp = (row & ~12) | ((row & 4) << 1) | ((row & 8) >> 1);  // s bits 2<->3
          ot[col * 136 + rowp] = f2b(v); // transposed for V
        } else {
          ot[row * 72 + col] = f2b(v);
        }
      }
    }
  }
  __syncthreads();

  // ---- coalesced stores (block = one head) ----
  int bb0 = m0 >> 11, sbase = m0 & 2047;
  int h = (n0 & 1023) >> 6;
  if (sec < 2) {
    uint16_t* dst0 = (sec == 0) ? Qb : Kb;
    int s_loc = t >> 1, half = t & 1;
    const uint16_t* src = ot + s_loc * 72 + half * 32;
    uint16_t* dst = dst0 + (((size_t)((bb0 * 16 + h) * 2048 + sbase + s_loc)) << 6) + half * 32;
#pragma unroll
    for (int c = 0; c < 4; ++c)
      *(u32x4*)(dst + c * 8) = *(const u32x4*)(src + c * 8);
  } else {
    int dh = t >> 2, qr = t & 3;
    const uint16_t* src = ot + dh * 136 + qr * 32;
    uint16_t* dst = Vt + ((size_t)((bb0 * 16 + h) * 64 + dh)) * 2048 + sbase + qr * 32;
#pragma unroll
    for (int c = 0; c < 4; ++c)
      *(u32x4*)(dst + c * 8) = *(const u32x4*)(src + c * 8);
  }
}

// ---------------- GEMM2: out = att @ w_out^T + b_out (f32 out) ----------------
// BM=128, BN=64, BK=64 dbuf (48KB), grid (16,32)=512 -> 2 blocks/CU resident.
__global__ __launch_bounds__(256) void gemm_out(const uint16_t* __restrict__ A,
                                                const uint16_t* __restrict__ W,
                                                const float* __restrict__ bias,
                                                float* __restrict__ out) {
  __shared__ uint8_t sm[49152];          // 2 x (A 16KB + B 8KB)
  int t = threadIdx.x, l = t & 63, w = t >> 6;
  int bid = (int)blockIdx.x + 16 * (int)blockIdx.y;
  int virt = (bid & 7) * 64 + (bid >> 3);
  int bx = virt % 16, by = virt / 16;
  int m0 = by * 128, n0 = bx * 64;
  int wr = (w >> 1) * 64, wc = (w & 1) * 32;
  const f32x4 fz = {0.f, 0.f, 0.f, 0.f};
  f32x4 acc[4][2];
#pragma unroll
  for (int i = 0; i < 4; ++i)
#pragma unroll
    for (int j = 0; j < 2; ++j) acc[i][j] = fz;

  const uint16_t* Ab_ = A + m0 * 1024;
  const uint16_t* Wb_ = W + n0 * 1024;
  stage64<4>(Ab_, 1024, sm, t);
  stage64<2>(Wb_, 1024, sm + 16384, t);

  for (int kt = 0; kt < 16; ++kt) {
    int cur = kt & 1;
    uint8_t* curb = sm + cur * 24576;
    asm volatile("s_waitcnt vmcnt(0)" ::: "memory");
    __syncthreads();
    if (kt + 1 < 16) {
      uint8_t* nb = sm + (cur ^ 1) * 24576;
      stage64<4>(Ab_ + (kt + 1) * 64, 1024, nb, t);
      stage64<2>(Wb_ + (kt + 1) * 64, 1024, nb + 16384, t);
    }
#pragma unroll
    for (int ks = 0; ks < 2; ++ks) {
      bf16x8 a[4], b[2];
#pragma unroll
      for (int i = 0; i < 4; ++i)
        a[i] = ld_frag(curb, wr + i * 16 + (l & 15), ks * 4 + (l >> 4));
#pragma unroll
      for (int j = 0; j < 2; ++j)
        b[j] = ld_frag(curb + 16384, wc + j * 16 + (l & 15), ks * 4 + (l >> 4));
#pragma unroll
      for (int i = 0; i < 4; ++i)
#pragma unroll
        for (int j = 0; j < 2; ++j)
          acc[i][j] = __builtin_amdgcn_mfma_f32_16x16x32_bf16(a[i], b[j], acc[i][j], 0, 0, 0);
    }
  }
#pragma unroll
  for (int j = 0; j < 2; ++j) {
    int e = n0 + wc + j * 16 + (l & 15);
    float bv = bias[e];
#pragma unroll
    for (int i = 0; i < 4; ++i) {
      int mb = m0 + wr + i * 16 + ((l >> 4) << 2);
#pragma unroll
      for (int r = 0; r < 4; ++r) {
        int m = mb + r;
        out[m * 1024 + e] = acc[i][j][r] + bv;
      }
    }
  }
}

// ---------------- Flash attention (causal): kv-halved dual-stream blocks ----------------
// Grid 512 = 16 supertiles x 32 bh, 512 threads (8 waves), 2 blocks/CU.
// Block = one 128-q-row supertile st. Group A (waves 0-3) consumes kv tiles
// [0, st+1); group B (waves 4-7) consumes [st+1, 2st+2) on its OWN dbuf stream.
// Fixed-reference softmax (P = exp2(s)); 2-way kv merge = plain sums.
__global__ __launch_bounds__(512) void attn(const uint16_t* __restrict__ Qb,
                                            const uint16_t* __restrict__ Kb,
                                            const uint16_t* __restrict__ Vt,
                                            uint16_t* __restrict__ Ab,
                                            const int* __restrict__ maskp) {
  __shared__ uint8_t smem[65536];      // 2 groups x 2 buffers x (K 8KB + V 8KB)
  int t = threadIdx.x, l = t & 63, w = t >> 6;   // w 0..7
  int hi = l >> 5, ql = l & 31;
  int g = w >> 2, wg = w & 3;          // kv-half group, wave-in-group
  int tl = t & 255;                    // group-local thread id
  // XCD bh-affinity: did%8 = XCD; 4 bh per XCD; heavy st first (r18 mapping).
  int did = (int)blockIdx.x;
  int xcd = did & 7, idx = did >> 3;   // idx 0..63
  int st = 15 - (idx >> 2);            // supertile, heavy first
  int bh = xcd * 4 + (idx & 3);
  bool causal = (*maskp != 0);
  int rounds = causal ? (st + 1) : 16;
  int tile0 = g * rounds;              // my group's first kv tile
  int q0w = st * 128 + wg * 32;        // wave's q base
  int q = q0w + ql;
  int bb = bh >> 4, h = bh & 15;

  const uint16_t* KpB = Kb + ((size_t)bh << 17);   // [2048][64]
  const uint16_t* VpB = Vt + ((size_t)bh << 17);   // [64][2048] col-permuted
  uint8_t* gbuf = smem + (g << 15);    // my group's 32KB stream region

  // Q fragments (B-operand): Q[q][dh = ks*16 + hi*8 + j], pre-scaled by CSQ
  bf16x8 qf[4];
  const uint16_t* Qp = Qb + (((size_t)bh * 2048 + q) << 6) + hi * 8;
#pragma unroll
  for (int ks = 0; ks < 4; ++ks) qf[ks] = *(const bf16x8*)(Qp + ks * 16);

  f32x16 acco[2];
#pragma unroll
  for (int r = 0; r < 16; ++r) { acco[0][r] = 0.f; acco[1][r] = 0.f; }
  float lsum = 0.f;

  // prologue: stage my group's tile0 into buffer 0 (256 threads x 2 issues/buf)
  stage64<2>(KpB + ((size_t)tile0 << 12), 64, gbuf, tl);
  stage64<2>(VpB + tile0 * 64, 2048, gbuf + 8192, tl);

  for (int rr = 0; rr < rounds; ++rr) {
    int tt = tile0 + rr;
    int cur = rr & 1;
    asm volatile("s_waitcnt vmcnt(0)" ::: "memory");   // my DMA landed
    __syncthreads();                                    // all landed; other bufs free
    if (rr + 1 < rounds) {                              // async prefetch (0 VGPR)
      uint8_t* nb = gbuf + ((cur ^ 1) << 14);
      stage64<2>(KpB + ((size_t)(tt + 1) << 12), 64, nb, tl);
      stage64<2>(VpB + (tt + 1) * 64, 2048, nb + 8192, tl);
    }
    if (causal && tt * 64 > q0w + 31) continue;        // fully masked for my rows

    const uint8_t* Ks = gbuf + (cur << 14);
    const uint8_t* Vs = Ks + 8192;
    bf16x8 kf[2][4], vf[2][4];
#pragma unroll
    for (int ks = 0; ks < 4; ++ks) {
      kf[0][ks] = ld_frag(Ks, ql,      ks * 2 + hi);
      kf[1][ks] = ld_frag(Ks, 32 + ql, ks * 2 + hi);
      vf[0][ks] = ld_frag(Vs, ql,      ks * 2 + hi);
      vf[1][ks] = ld_frag(Vs, 32 + ql, ks * 2 + hi);
    }

    // ---- QK^T: sc[f][r] = S[kv = tt*64 + f*32 + crow(r,hi)][q] (log2 units) ----
    f32x16 sc[2];
#pragma unroll
    for (int r = 0; r < 16; ++r) { sc[0][r] = 0.f; sc[1][r] = 0.f; }
    __builtin_amdgcn_s_setprio(1);
#pragma unroll
    for (int ks = 0; ks < 4; ++ks)
      sc[0] = __builtin_amdgcn_mfma_f32_32x32x16_bf16(kf[0][ks], qf[ks], sc[0], 0, 0, 0);
#pragma unroll
    for (int ks = 0; ks < 4; ++ks)
      sc[1] = __builtin_amdgcn_mfma_f32_32x32x16_bf16(kf[1][ks], qf[ks], sc[1], 0, 0, 0);
    __builtin_amdgcn_s_setprio(0);

    bool nomask = (!causal) || (tt * 64 + 63 <= q0w);
    int qrel = q - tt * 64;
    float rs0 = 0.f, rs1 = 0.f, rs2 = 0.f, rs3 = 0.f;

    // ---- exp half f=0 (overlaps QK f=1 MFMA latency) ----
#pragma unroll
    for (int r = 0; r < 16; ++r) {
      float v = sc[0][r];
      if (!nomask) {
        int kv = (r & 3) + 8 * (r >> 2) + 4 * hi;
        v = (kv <= qrel) ? v : -1e30f;
      }
      float e = fexp2(v);
      sc[0][r] = e;
      if (r & 1) rs1 += e; else rs0 += e;
    }

    // ---- PV ks=0,1 (uses sc[0]) ----
    __builtin_amdgcn_s_setprio(1);
#pragma unroll
    for (int ks = 0; ks < 2; ++ks) {
      int a8 = ks * 8;
      u32x4 wv = {cvtpk(sc[0][a8 + 0], sc[0][a8 + 1]),
                  cvtpk(sc[0][a8 + 2], sc[0][a8 + 3]),
                  cvtpk(sc[0][a8 + 4], sc[0][a8 + 5]),
                  cvtpk(sc[0][a8 + 6], sc[0][a8 + 7])};
      bf16x8 af = __builtin_bit_cast(bf16x8, wv);
      acco[0] = __builtin_amdgcn_mfma_f32_32x32x16_bf16(af, vf[0][ks], acco[0], 0, 0, 0);
      acco[1] = __builtin_amdgcn_mfma_f32_32x32x16_bf16(af, vf[1][ks], acco[1], 0, 0, 0);
    }
    __builtin_amdgcn_s_setprio(0);

    // ---- exp half f=1 ----
#pragma unroll
    for (int r = 0; r < 16; ++r) {
      float v = sc[1][r];
      if (!nomask) {
        int kv = 32 + (r & 3) + 8 * (r >> 2) + 4 * hi;
        v = (kv <= qrel) ? v : -1e30f;
      }
      float e = fexp2(v);
      sc[1][r] = e;
      if (r & 1) rs3 += e; else rs2 += e;
    }

    // ---- PV ks=2,3 (uses sc[1]) ----
    __builtin_amdgcn_s_setprio(1);
#pragma unroll
    for (int ks = 0; ks < 2; ++ks) {
      int a8 = ks * 8;
      u32x4 wv = {cvtpk(sc[1][a8 + 0], sc[1][a8 + 1]),
                  cvtpk(sc[1][a8 + 2], sc[1][a8 + 3]),
                  cvtpk(sc[1][a8 + 4], sc[1][a8 + 5]),
                  cvtpk(sc[1][a8 + 6], sc[1][a8 + 7])};
      bf16x8 af = __builtin_bit_cast(bf16x8, wv);
      acco[0] = __builtin_amdgcn_mfma_f32_32x32x16_bf16(af, vf[0][ks + 2], acco[0], 0, 0, 0);
      acco[1] = __builtin_amdgcn_mfma_f32_32x32x16_bf16(af, vf[1][ks + 2], acco[1], 0, 0, 0);
    }
    __builtin_amdgcn_s_setprio(0);

    lsum += (rs0 + rs1) + (rs2 + rs3);
  }

  // ---- 2-way kv-half merge (plain sums; LDS aliases stream buffers) ----
  __syncthreads();                     // all loops done; safe to alias LDS
  lsum += __shfl_xor(lsum, 32);        // lanes ql / ql+32 both hold full row-sum
  float (*oaccS)[64][33] = (float(*)[64][33])smem;          // [4][64][33]
  float (*lsumS)[64]     = (float(*)[64])(smem + 33792);    // [4][64]
  if (g == 1) {
#pragma unroll
    for (int r = 0; r < 16; ++r) {
      oaccS[wg][l][r] = acco[0][r];
      oaccS[wg][l][16 + r] = acco[1][r];
    }
    lsumS[wg][l] = lsum;
  }
  __syncthreads();
  if (g == 0) {
#pragma unroll
    for (int r = 0; r < 16; ++r) {
      acco[0][r] += oaccS[wg][l][r];
      acco[1][r] += oaccS[wg][l][16 + r];
    }
    lsum += lsumS[wg][l];
#pragma unroll
    for (int r = 0; r < 16; ++r) {
      int crow = (r & 3) + 8 * (r >> 2) + 4 * hi;
      float L = __shfl(lsum, crow);
      float inv = 1.0f / L;
      int qg = q0w + crow;
#pragma unroll
      for (int n = 0; n < 2; ++n)
        Ab[(((size_t)(bb * 2048 + qg)) << 10) + h * 64 + n * 32 + ql] = f2b(acco[n][r] * inv);
    }
  }
}

extern "C" void kernel_launch(void* const* d_in, const int* in_sizes, int n_in,
                              void* d_out, int out_size, void* d_ws, size_t ws_size,
                              hipStream_t stream) {
  const float* x     = (const float*)d_in[0];
  const float* w_in  = (const float*)d_in[1];
  const float* b_in  = (const float*)d_in[2];
  const float* w_out = (const float*)d_in[3];
  const float* b_out = (const float*)d_in[4];
  const int*   mask  = (const int*)d_in[5];
  float* out = (float*)d_out;

  uint8_t* ws = (uint8_t*)d_ws;
  uint16_t* xb  = (uint16_t*)(ws);                  // 8 MB  x bf16 [4096][1024]
  uint16_t* wib = (uint16_t*)(ws + (8u << 20));     // 6 MB  w_in bf16 [3072][1024]
  uint16_t* wob = (uint16_t*)(ws + (14u << 20));    // 2 MB  w_out bf16 [1024][1024]
  uint16_t* Qb  = (uint16_t*)(ws + (16u << 20));    // 8 MB  (B,H,S,DH) pre-scaled
  uint16_t* Kb  = (uint16_t*)(ws + (24u << 20));    // 8 MB  (B,H,S,DH)
  uint16_t* Vt  = (uint16_t*)(ws + (32u << 20));    // 8 MB  (B,H,DH,S) col-permuted
  uint16_t* Ab  = (uint16_t*)(ws + (40u << 20));    // 8 MB  att (B,S,D) bf16

  cvt3<<<8192, 256, 0, stream>>>(x, w_in, w_out, xb, wib, wob);
  gemm_qkv<<<dim3(48, 32), 256, 0, stream>>>(xb, wib, b_in, Qb, Kb, Vt);
  attn<<<512, 512, 0, stream>>>(Qb, Kb, Vt, Ab, mask);
  gemm_out<<<dim3(16, 32), 256, 0, stream>>>(Ab, wob, b_out, out);
}